// Round 2
// baseline (1006.042 us; speedup 1.0000x reference)
//
#include <hip/hip_runtime.h>

namespace {
constexpr int Bn = 2, Dn = 48, Hn = 320, Wn = 640;
constexpr int R = 2, K = 5, K2 = 25, C3 = 75;
constexpr int TW = 64, TH = 4;
constexpr int LW = TW + 2 * R;   // 68
constexpr int LH = TH + 2 * R;   // 8
constexpr int NT = TW * TH;      // 256
constexpr int LTOT = LH * LW;    // 544
}

// out[b,d,h,w] = sum_{ij} w0*x[d] + w1*x[d-1] + w2*x[d+1] over 5x5 window.
// Reformulated: Sg(p) = sum_ij wg[ij]*win_p[ij]; out[d] = S0(d)+S1(d-1)+S2(d+1).
// One 25-reg window per plane + 2 carry scalars (no 3-window rolling state -> no spill).
// 3-deep plane pipeline: issue loads for p+3 at step p, commit p+2 (issued at p-1),
// read p at step p. vmcnt wait is always on step-old loads.
__global__ __launch_bounds__(NT, 4)
void lga_pass(const float* __restrict__ x, const float* __restrict__ wt,
              float* __restrict__ out) {
    __shared__ float pl[3][LTOT];

    const int tx = threadIdx.x;          // 0..63 (w)
    const int ty = threadIdx.y;          // 0..3  (h)
    const int tid = ty * TW + tx;

    const int w0pix = blockIdx.x * TW;
    const int h0pix = blockIdx.y * TH;
    const int b = blockIdx.z;

    const int gw = w0pix + tx;
    const int gh = h0pix + ty;

    const size_t ps = (size_t)Hn * Wn;

    // ---- precompute staging offsets once (3 chunks of NT threads cover LTOT) ----
    int  soff[3];
    bool svalid[3];
#pragma unroll
    for (int t = 0; t < 3; ++t) {
        int idx = tid + t * NT;
        int rr = idx / LW;
        int cc = idx - rr * LW;
        int hh = h0pix - R + rr;
        int ww = w0pix - R + cc;
        bool ok = (idx < LTOT) && hh >= 0 && hh < Hn && ww >= 0 && ww < Wn;
        soff[t] = ok ? (hh * Wn + ww) : 0;
        svalid[t] = ok;
    }

    const float* xb = x + (size_t)b * Dn * ps;

    // ---- 75 per-pixel guidance weights into registers (reused over all 48 d) ----
    float wr[C3];
    {
        const float* wp = wt + (size_t)b * C3 * ps + (size_t)gh * Wn + gw;
#pragma unroll
        for (int c = 0; c < C3; ++c) wr[c] = wp[(size_t)c * ps];
    }

    float* ob = out + (size_t)b * Dn * ps + (size_t)gh * Wn + gw;

    // issue global loads for one plane's tile into registers
    auto issue = [&](int plane, float (&stg)[3]) {
        const bool pv = plane < Dn;
        const float* src = xb + (size_t)plane * ps;
#pragma unroll
        for (int t = 0; t < 3; ++t)
            stg[t] = (pv && svalid[t]) ? src[soff[t]] : 0.f;
    };
    // commit staged registers to an LDS slot
    auto commit = [&](int slot, const float (&stg)[3]) {
#pragma unroll
        for (int t = 0; t < 3; ++t) {
            int idx = tid + t * NT;
            if (t < 2 || idx < LTOT) pl[slot][idx] = stg[t];
        }
    };

    // one d-step: read plane p's window, 3 dot products, store out[p-1],
    // issue p+3, commit p+2 (in stgC), barrier.
    auto step = [&](int p, int slotR, int slotW,
                    float (&stgI)[3], const float (&stgC)[3],
                    float& carry, float& s1prev) {
        issue(p + 3, stgI);
        float win[K2];
#pragma unroll
        for (int i = 0; i < K; ++i)
#pragma unroll
            for (int j = 0; j < K; ++j)
                win[i * K + j] = pl[slotR][(ty + i) * LW + tx + j];
        float S0 = 0.f, S1 = 0.f, S2 = 0.f;
#pragma unroll
        for (int q = 0; q < K2; ++q) S0 += wr[q] * win[q];
#pragma unroll
        for (int q = 0; q < K2; ++q) S1 += wr[K2 + q] * win[q];
#pragma unroll
        for (int q = 0; q < K2; ++q) S2 += wr[2 * K2 + q] * win[q];
        if (p > 0) ob[(size_t)(p - 1) * ps] = carry + S2;
        carry = S0 + s1prev;
        s1prev = S1;
        commit(slotW, stgC);
        __syncthreads();
    };

    // prologue: planes 0,1 direct to slots 0,1; issue plane 2 into stgB
    float stgA[3], stgB[3];
    {
        float s[3];
        issue(0, s); commit(0, s);
        issue(1, s); commit(1, s);
    }
    issue(2, stgB);
    __syncthreads();

    float carry = 0.f, s1prev = 0.f;
    // slotR = p%3, slotW = (p+2)%3, stg sets alternate; period 6
    for (int d0 = 0; d0 < Dn; d0 += 6) {
        step(d0 + 0, 0, 2, stgA, stgB, carry, s1prev);
        step(d0 + 1, 1, 0, stgB, stgA, carry, s1prev);
        step(d0 + 2, 2, 1, stgA, stgB, carry, s1prev);
        step(d0 + 3, 0, 2, stgB, stgA, carry, s1prev);
        step(d0 + 4, 1, 0, stgA, stgB, carry, s1prev);
        step(d0 + 5, 2, 1, stgB, stgA, carry, s1prev);
    }
    // out[D-1] = S0(D-1) + S1(D-2)  (S2(D) = 0)
    ob[(size_t)(Dn - 1) * ps] = carry;
}

extern "C" void kernel_launch(void* const* d_in, const int* in_sizes, int n_in,
                              void* d_out, int out_size, void* d_ws, size_t ws_size,
                              hipStream_t stream) {
    const float* x = (const float*)d_in[0];
    const float* w = (const float*)d_in[1];
    // d_in[2] = radius (always 2 here; compile-time constant)
    float* out = (float*)d_out;
    float* tmp = (float*)d_ws;   // intermediate y

    dim3 block(TW, TH, 1);
    dim3 grid(Wn / TW, Hn / TH, Bn);

    lga_pass<<<grid, block, 0, stream>>>(x, w, tmp);
    lga_pass<<<grid, block, 0, stream>>>(tmp, w, out);
}

// Round 4
// 866.733 us; speedup vs baseline: 1.1607x; 1.1607x over previous
//
#include <hip/hip_runtime.h>

namespace {
constexpr int Bn = 2, Dn = 48, Hn = 320, Wn = 640;
constexpr int R = 2, K = 5, K2 = 25, C3 = 75;
constexpr int TW = 64, TH = 4;        // block = 4 waves; wave ty owns one output row
constexpr int LW = TW + 2 * R;        // 68
constexpr int WTILE = K * LW;         // 340 floats = one wave's 5-row halo tile
constexpr int NCHUNK = (WTILE + 63) / 64;  // 6 (last chunk: 20 lanes)
}

// Zero-cost in-wave ordering point: compiler memory fence + wave barrier.
// Emits no instructions. Required because cross-LANE LDS handoff has no
// per-thread dependence edge in LLVM's model — without this the scheduler
// hoists ds_reads across the ds_writes of the same slot (R3's failure).
// Hardware executes a wave's DS ops in order, so compiler order == correct.
#define WAVE_LDS_FENCE()                     \
    do {                                     \
        __builtin_amdgcn_wave_barrier();     \
        asm volatile("" ::: "memory");       \
    } while (0)

// out[b,d,h,w] = sum_{ij in 5x5} w0*x[d] + w1*x[d-1] + w2*x[d+1], zero-padded.
// Reformulated: Sg(p) = sum_ij wg[ij]*win_p[ij]; out[d] = S0(d)+S1(d-1)+S2(d+1)
//   -> one 25-reg window per plane + 2 carry scalars.
// LDS tiles are WAVE-PRIVATE (5x68 per plane, 3 rotating slots): no s_barrier
// anywhere; ordering is the WAVE_LDS_FENCE at each step.
// Plane pipeline: at step p, issue global loads for p+3, commit p+2 (loaded at
// step p-1) to LDS, read window p, compute, store out[p-1].
__global__ __launch_bounds__(256, 3)
void lga_pass(const float* __restrict__ x, const float* __restrict__ wt,
              float* __restrict__ out) {
    __shared__ float pl[TH][3][WTILE];

    const int lane = threadIdx.x;     // 0..63 (w)
    const int wv   = threadIdx.y;     // 0..3  wave id = row within block
    const int w0   = blockIdx.x * TW;
    const int gh   = blockIdx.y * TH + wv;
    const int b    = blockIdx.z;
    const int gw   = w0 + lane;
    const size_t ps = (size_t)Hn * Wn;

    // staging offsets for this wave's 5x68 tile (hoisted: includes the /68)
    int  soff[NCHUNK];
    bool sval[NCHUNK];
#pragma unroll
    for (int t = 0; t < NCHUNK; ++t) {
        int idx = lane + t * 64;
        int rr = idx / LW;
        int cc = idx - rr * LW;
        int hh = gh - R + rr;
        int ww = w0 - R + cc;
        bool ok = (idx < WTILE) && hh >= 0 && hh < Hn && ww >= 0 && ww < Wn;
        sval[t] = ok;
        soff[t] = ok ? (hh * Wn + ww) : 0;
    }

    const float* xb = x + (size_t)b * Dn * ps;
    float* ob = out + (size_t)b * Dn * ps + (size_t)gh * Wn + gw;

    // 75 per-pixel guidance weights -> registers (reused across all 48 planes)
    float wr[C3];
    {
        const float* wp = wt + (size_t)b * C3 * ps + (size_t)gh * Wn + gw;
#pragma unroll
        for (int c = 0; c < C3; ++c) wr[c] = wp[(size_t)c * ps];
    }

    float (*myl)[WTILE] = pl[wv];

    auto issue = [&](int p, float (&g)[NCHUNK]) {
        const float* src = xb + (size_t)p * ps;
        const bool pv = p < Dn;
#pragma unroll
        for (int t = 0; t < NCHUNK; ++t)
            g[t] = (pv && sval[t]) ? src[soff[t]] : 0.f;
    };
    auto commit = [&](int slot, const float (&g)[NCHUNK]) {
#pragma unroll
        for (int t = 0; t < NCHUNK; ++t) {
            int idx = lane + t * 64;
            if (t < NCHUNK - 1 || idx < WTILE) myl[slot][idx] = g[t];
        }
    };

    // one d-step (all slot/reg roles compile-time at call sites)
    auto step = [&](int p, int slotR, int slotW,
                    float (&gI)[NCHUNK], const float (&gC)[NCHUNK],
                    float& carry, float& s1prev) {
        WAVE_LDS_FENCE();   // orders commit@p-2 -> loadwin@p, loadwin@p-1 -> commit@p
        issue(p + 3, gI);                       // VMEM for plane p+3 in flight
        float win[K2];                          // read window p (slotR != slotW)
#pragma unroll
        for (int i = 0; i < K; ++i)
#pragma unroll
            for (int j = 0; j < K; ++j)
                win[i * K + j] = myl[slotR][i * LW + lane + j];
        commit(slotW, gC);                      // plane p+2; vmcnt on step-old loads
        float S0 = 0.f, S1 = 0.f, S2 = 0.f;
#pragma unroll
        for (int q = 0; q < K2; ++q) S0 += wr[q] * win[q];
#pragma unroll
        for (int q = 0; q < K2; ++q) S1 += wr[K2 + q] * win[q];
#pragma unroll
        for (int q = 0; q < K2; ++q) S2 += wr[2 * K2 + q] * win[q];
        if (p > 0) ob[(size_t)(p - 1) * ps] = carry + S2;
        carry = S0 + s1prev;
        s1prev = S1;
    };

    // prologue: planes 0,1 staged; plane 2 in flight in gB
    float gA[NCHUNK], gB[NCHUNK];
    issue(0, gA); commit(0, gA);
    WAVE_LDS_FENCE();
    issue(1, gA); commit(1, gA);
    issue(2, gB);

    float carry = 0.f, s1prev = 0.f;
    // slotR = p%3, slotW = (p+2)%3; staging reg sets alternate; period 6
    for (int d0 = 0; d0 < Dn; d0 += 6) {
        step(d0 + 0, 0, 2, gA, gB, carry, s1prev);
        step(d0 + 1, 1, 0, gB, gA, carry, s1prev);
        step(d0 + 2, 2, 1, gA, gB, carry, s1prev);
        step(d0 + 3, 0, 2, gB, gA, carry, s1prev);
        step(d0 + 4, 1, 0, gA, gB, carry, s1prev);
        step(d0 + 5, 2, 1, gB, gA, carry, s1prev);
    }
    // out[D-1] = S0(D-1) + S1(D-2)   (S2 of plane D is zero)
    ob[(size_t)(Dn - 1) * ps] = carry;
}

extern "C" void kernel_launch(void* const* d_in, const int* in_sizes, int n_in,
                              void* d_out, int out_size, void* d_ws, size_t ws_size,
                              hipStream_t stream) {
    const float* x = (const float*)d_in[0];
    const float* w = (const float*)d_in[1];
    // d_in[2] = radius (always 2 here; compile-time constant)
    float* out = (float*)d_out;
    float* tmp = (float*)d_ws;   // intermediate y (78.6 MB)

    dim3 block(TW, TH, 1);
    dim3 grid(Wn / TW, Hn / TH, Bn);

    lga_pass<<<grid, block, 0, stream>>>(x, w, tmp);
    lga_pass<<<grid, block, 0, stream>>>(tmp, w, out);
}

// Round 5
// 463.244 us; speedup vs baseline: 2.1717x; 1.8710x over previous
//
#include <hip/hip_runtime.h>

namespace {
constexpr int Bn = 2, Dn = 48, Hn = 320, Wn = 640;
constexpr int R = 2, K = 5, K2 = 25, C3 = 75;
constexpr int TW = 64, TH = 4;
constexpr int LW = TW + 2 * R;   // 68
constexpr int LH = TH + 2 * R;   // 8
constexpr int NT = TW * TH;      // 256
constexpr int LTOT = LH * LW;    // 544
constexpr int NCH = 3;           // staging chunks (2 full + 1 partial of 32 lanes)
constexpr int NSLOT = 4;         // LDS plane slots
}

// out[b,d,h,w] = sum_{ij in 5x5} w0*x[d] + w1*x[d-1] + w2*x[d+1], zero-padded.
// Reformulated: Sg(p) = sum_ij wg[ij]*win_p[ij]; out[d] = S0(d)+S1(d-1)+S2(d+1)
//   -> ONE 25-elem window per plane + 2 carry scalars (minimal live state).
// Block-shared staging (2.1 loads/thread/plane), 4 rotating LDS slots.
// 2-deep VMEM pipeline: step p issues plane p+4, commits plane p+2 (issued at
// p-2; vmcnt covers 2 steps of FMAs), reads window p, stores out[p-1].
// Barrier every 2 steps: slots read {p,p+1} and committed {p+2,p+3} are all
// distinct mod 4, so one __syncthreads per pair orders all WAR/RAW hazards.
__global__ __launch_bounds__(NT, 2)
void lga_pass(const float* __restrict__ x, const float* __restrict__ wt,
              float* __restrict__ out) {
    __shared__ float pl[NSLOT][LTOT];

    const int tx = threadIdx.x;          // 0..63 (w)
    const int ty = threadIdx.y;          // 0..3  (h)
    const int tid = ty * TW + tx;

    const int w0pix = blockIdx.x * TW;
    const int h0pix = blockIdx.y * TH;
    const int b = blockIdx.z;

    const int gw = w0pix + tx;
    const int gh = h0pix + ty;

    const size_t ps = (size_t)Hn * Wn;

    // ---- staging offsets (hoisted: includes the /68) ----
    int  soff[NCH];
    bool sval[NCH];
#pragma unroll
    for (int t = 0; t < NCH; ++t) {
        int idx = tid + t * NT;
        int rr = idx / LW;
        int cc = idx - rr * LW;
        int hh = h0pix - R + rr;
        int ww = w0pix - R + cc;
        bool ok = (idx < LTOT) && hh >= 0 && hh < Hn && ww >= 0 && ww < Wn;
        sval[t] = ok;
        soff[t] = ok ? (hh * Wn + ww) : 0;
    }

    const float* xb = x + (size_t)b * Dn * ps;

    // ---- 75 per-pixel guidance weights -> registers (reused over 48 planes) ----
    float wr[C3];
    {
        const float* wp = wt + (size_t)b * C3 * ps + (size_t)gh * Wn + gw;
#pragma unroll
        for (int c = 0; c < C3; ++c) wr[c] = wp[(size_t)c * ps];
    }

    float* op = out + (size_t)b * Dn * ps + (size_t)gh * Wn + gw;
    const int lbase = ty * LW + tx;      // window base within a slot

    auto issue = [&](int p, float (&g)[NCH]) {
        const float* src = xb + (size_t)p * ps;
        const bool pv = p < Dn;
#pragma unroll
        for (int t = 0; t < NCH; ++t)
            g[t] = (pv && sval[t]) ? src[soff[t]] : 0.f;
    };
    auto commit = [&](int slot, const float (&g)[NCH]) {
#pragma unroll
        for (int t = 0; t < NCH; ++t) {
            int idx = tid + t * NT;
            if (t < NCH - 1 || idx < LTOT) pl[slot][idx] = g[t];
        }
    };

    float carry = 0.f, s1prev = 0.f;

    // one d-step; all slot/gset roles are literals at call sites
    auto step = [&](int p, int sR, int sC,
                    float (&gI)[NCH], const float (&gC)[NCH]) {
        issue(p + 4, gI);                        // plane p+4 into flight
        float S0 = 0.f, S1 = 0.f, S2 = 0.f;
#pragma unroll
        for (int i = 0; i < K; ++i) {            // row-interleaved: 5 live vals
            float v0 = pl[sR][lbase + i * LW + 0];
            float v1 = pl[sR][lbase + i * LW + 1];
            float v2 = pl[sR][lbase + i * LW + 2];
            float v3 = pl[sR][lbase + i * LW + 3];
            float v4 = pl[sR][lbase + i * LW + 4];
            S0 += wr[i*K+0]*v0 + wr[i*K+1]*v1 + wr[i*K+2]*v2 + wr[i*K+3]*v3 + wr[i*K+4]*v4;
            S1 += wr[K2+i*K+0]*v0 + wr[K2+i*K+1]*v1 + wr[K2+i*K+2]*v2 + wr[K2+i*K+3]*v3 + wr[K2+i*K+4]*v4;
            S2 += wr[2*K2+i*K+0]*v0 + wr[2*K2+i*K+1]*v1 + wr[2*K2+i*K+2]*v2 + wr[2*K2+i*K+3]*v3 + wr[2*K2+i*K+4]*v4;
        }
        commit(sC, gC);                          // plane p+2 (issued at p-2)
        if (p > 0) { *op = carry + S2; op += ps; }
        carry = S0 + s1prev;
        s1prev = S1;
    };

    // prologue: planes 0,1 direct into slots 0,1; planes 2,3 in flight
    float G0[NCH], G1[NCH], G2[NCH];
    {
        float t[NCH];
        issue(0, t); commit(0, t);
        issue(1, t); commit(1, t);
    }
    issue(2, G1);
    issue(3, G2);
    __syncthreads();

    // p = d0+k: slotR = p%4, slotC = (p+2)%4, GI = G[p%3], GC = G[(p+1)%3]
    for (int d0 = 0; d0 < Dn; d0 += 12) {
        step(d0 + 0, 0, 2, G0, G1);
        step(d0 + 1, 1, 3, G1, G2);
        __syncthreads();
        step(d0 + 2, 2, 0, G2, G0);
        step(d0 + 3, 3, 1, G0, G1);
        __syncthreads();
        step(d0 + 4, 0, 2, G1, G2);
        step(d0 + 5, 1, 3, G2, G0);
        __syncthreads();
        step(d0 + 6, 2, 0, G0, G1);
        step(d0 + 7, 3, 1, G1, G2);
        __syncthreads();
        step(d0 + 8, 0, 2, G2, G0);
        step(d0 + 9, 1, 3, G0, G1);
        __syncthreads();
        step(d0 + 10, 2, 0, G1, G2);
        step(d0 + 11, 3, 1, G2, G0);
        if (d0 + 12 < Dn) __syncthreads();
    }
    // out[D-1] = S0(D-1) + S1(D-2)   (S2 of plane D is zero)
    *op = carry;
}

extern "C" void kernel_launch(void* const* d_in, const int* in_sizes, int n_in,
                              void* d_out, int out_size, void* d_ws, size_t ws_size,
                              hipStream_t stream) {
    const float* x = (const float*)d_in[0];
    const float* w = (const float*)d_in[1];
    // d_in[2] = radius (always 2 here; compile-time constant)
    float* out = (float*)d_out;
    float* tmp = (float*)d_ws;   // intermediate y (78.6 MB)

    dim3 block(TW, TH, 1);
    dim3 grid(Wn / TW, Hn / TH, Bn);

    lga_pass<<<grid, block, 0, stream>>>(x, w, tmp);
    lga_pass<<<grid, block, 0, stream>>>(tmp, w, out);
}